// Round 10
// baseline (79.762 us; speedup 1.0000x reference)
//
#include <hip/hip_runtime.h>
#include <hip/hip_bf16.h>

#define Bimg 32
#define Mgt 256
#define Nprop 4000
#define KBOX (Nprop + Mgt)   // 4256
#define NCLS 80
#define BATCH 512
#define NFG_CAP 128
#define NBINS 1024
#define BINCAP 1024
#define MT 32                 // m-rows per block
#define MS (Mgt / MT)         // 8 m-slices
#define NCHA 8                // A: column chunks  (8 * 532 = 4256 exact)
#define CW 532                // A: columns per chunk (even -> no prop/gt straddle)
#define NU (CW / 2)           // A: 266 f32x2 units per chunk
#define KCHB ((KBOX + 511) / 512)               // 9 chunks (decode, 2/thread)

typedef float f32x2 __attribute__((ext_vector_type(2)));
typedef unsigned long long ull;

// ---------------- Kernel A: IoU tiles + per-slice partial argmax ----------------
__global__ __launch_bounds__(256) void iou_part_kernel(
    const float* __restrict__ gt_boxes,     // [B,M,4]
    const float* __restrict__ prop_boxes,   // [B,N,4]
    float* __restrict__ out_iou,            // [B,M,K]
    ull* __restrict__ part)                 // [B,MS,K] packed keys
{
    const int b    = blockIdx.z;
    const int ms   = blockIdx.y;
    const int m0   = ms * MT;
    const int base = blockIdx.x * CW;

    __shared__ float4 gbox[MT];
    __shared__ float  garea[MT];
    if (threadIdx.x < MT) {
        float4 g = ((const float4*)(gt_boxes + (size_t)b * Mgt * 4))[m0 + threadIdx.x];
        gbox[threadIdx.x] = g;
        garea[threadIdx.x] = (g.z - g.x) * (g.w - g.y);
    }
    __syncthreads();

    for (int u = threadIdx.x; u < NU; u += 256) {
        const int k0 = base + 2 * u;   // even; prop/gt boundary (4000) never straddled

        float4 bx0, bx1;
        if (k0 < Nprop) {
            const float4* pp = (const float4*)(prop_boxes + (size_t)b * Nprop * 4);
            bx0 = pp[k0]; bx1 = pp[k0 + 1];
        } else {
            const float4* gg = (const float4*)(gt_boxes + (size_t)b * Mgt * 4);
            bx0 = gg[k0 - Nprop]; bx1 = gg[k0 + 1 - Nprop];
        }
        const float a20 = (bx0.z - bx0.x) * (bx0.w - bx0.y);
        const float a21 = (bx1.z - bx1.x) * (bx1.w - bx1.y);

        float bestv0 = -1.f, bestv1 = -1.f;
        int   bestm0 = 0,    bestm1 = 0;
        float* orow = out_iou + (size_t)b * Mgt * KBOX + (size_t)m0 * KBOX + k0;

        for (int mm = 0; mm < MT; ++mm) {
            float4 g = gbox[mm];
            float ga = garea[mm];
            // column 0
            float ltx0 = fmaxf(g.x, bx0.x), lty0 = fmaxf(g.y, bx0.y);
            float rbx0 = fminf(g.z, bx0.z), rby0 = fminf(g.w, bx0.w);
            float w0 = fmaxf(rbx0 - ltx0, 0.0f), h0 = fmaxf(rby0 - lty0, 0.0f);
            float inter0 = w0 * h0;
            float uni0 = ga + a20 - inter0;          // >= 16 always (min side 4)
            float r0 = __builtin_amdgcn_rcpf(uni0);
            r0 = fmaf(fmaf(-uni0, r0, 1.0f), r0, r0);
            float io0 = inter0 * r0;                 // inter==0 -> exactly +0
            // column 1
            float ltx1 = fmaxf(g.x, bx1.x), lty1 = fmaxf(g.y, bx1.y);
            float rbx1 = fminf(g.z, bx1.z), rby1 = fminf(g.w, bx1.w);
            float w1 = fmaxf(rbx1 - ltx1, 0.0f), h1 = fmaxf(rby1 - lty1, 0.0f);
            float inter1 = w1 * h1;
            float uni1 = ga + a21 - inter1;
            float r1 = __builtin_amdgcn_rcpf(uni1);
            r1 = fmaf(fmaf(-uni1, r1, 1.0f), r1, r1);
            float io1 = inter1 * r1;

            if (io0 > bestv0) { bestv0 = io0; bestm0 = m0 + mm; }  // strict > == first-argmax
            if (io1 > bestv1) { bestv1 = io1; bestm1 = m0 + mm; }

            f32x2 res = { io0, io1 };
            __builtin_nontemporal_store(res, (f32x2*)(orow + (size_t)mm * KBOX));
        }

        ull bk0 = ((ull)__float_as_uint(bestv0) << 8) | (ull)(255 - bestm0);
        ull bk1 = ((ull)__float_as_uint(bestv1) << 8) | (ull)(255 - bestm1);
        *(ulonglong2*)(part + ((size_t)b * MS + ms) * KBOX + k0) =
            make_ulonglong2(bk0, bk1);   // max-key == (max iou, min m)
    }
}

// ---------------- Kernel B1: parallel decode + keys + per-block histograms ----------------
__global__ __launch_bounds__(256) void decode_kernel(
    const int*   __restrict__ gt_classes,   // [B,M]
    const float* __restrict__ pri,          // [B,K]
    const ull*   __restrict__ part,         // [B,MS,K]
    float* __restrict__ out_midx,           // [B,K]
    float* __restrict__ out_mlab,           // [B,K]
    ull*   __restrict__ keysG,              // [B,K]
    int*   __restrict__ histG)              // [B,KCHB,NBINS] packed fg|bg
{
    const int b   = blockIdx.y;
    const int ch  = blockIdx.x;
    const int tid = threadIdx.x;

    __shared__ int histL[NBINS];
    __shared__ int gcls[Mgt];
    *(int4*)&histL[tid * 4] = make_int4(0, 0, 0, 0);
    gcls[tid] = gt_classes[b * Mgt + tid];
    __syncthreads();

    const int i0 = ch * 512 + tid * 2;
    if (i0 < KBOX) {
        const ull* p0 = part + (size_t)b * MS * KBOX + i0;
        ulonglong2 bk2 = *(const ulonglong2*)p0;
        ull bk[2] = { bk2.x, bk2.y };
        #pragma unroll
        for (int s = 1; s < MS; ++s) {
            ulonglong2 t = *(const ulonglong2*)(p0 + (size_t)s * KBOX);
            bk[0] = (t.x > bk[0]) ? t.x : bk[0];
            bk[1] = (t.y > bk[1]) ? t.y : bk[1];
        }
        f32x2 pv = *(const f32x2*)(pri + (size_t)b * KBOX + i0);
        float mi2[2], ml2[2]; ull kk[2];
        #pragma unroll
        for (int c = 0; c < 2; ++c) {
            float v  = __uint_as_float((unsigned)(bk[c] >> 8));
            int   mi = 255 - (int)(bk[c] & 0xFFull);
            bool  fg = (v >= 0.5f);
            int  cls = fg ? gcls[mi] : NCLS;
            mi2[c] = (float)mi;
            ml2[c] = fg ? 1.0f : 0.0f;
            float p = pv[c];
            unsigned pb = __float_as_uint(p);   // pri in [0,1): monotone as uint
            kk[c] = ((ull)pb << 32) |
                    ((ull)(0xFFFFu - (unsigned)(i0 + c)) << 16) |
                    ((ull)(unsigned)cls << 8);
            int bucket = (int)(p * (float)NBINS);
            bucket = min(max(bucket, 0), NBINS - 1);
            atomicAdd(&histL[bucket], fg ? 1 : (1 << 16));
        }
        *(f32x2*)(out_midx + (size_t)b * KBOX + i0) = f32x2{ mi2[0], mi2[1] };
        *(f32x2*)(out_mlab + (size_t)b * KBOX + i0) = f32x2{ ml2[0], ml2[1] };
        *(ulonglong2*)(keysG + (size_t)b * KBOX + i0) = make_ulonglong2(kk[0], kk[1]);
    }
    __syncthreads();
    int4 h = *(int4*)&histL[tid * 4];
    *(int4*)&histG[((size_t)(b * KCHB + ch)) * NBINS + tid * 4] = h;
}

// ---------------- Kernel B2: scan + select + rank-order (1 block / image) ----------------
__global__ __launch_bounds__(1024) void sample_kernel(
    const ull* __restrict__ keysG,          // [B,K]
    const int* __restrict__ histG,          // [B,KCHB,NBINS]
    float* __restrict__ out_idx,            // [B,512]
    float* __restrict__ out_lab)            // [B,512]
{
    const int b    = blockIdx.x;
    const int tid  = threadIdx.x;
    const int lane = tid & 63;
    const int wv   = tid >> 6;              // 16 waves

    __shared__ ull keys[KBOX];                    // 34 KB
    __shared__ unsigned char selA[KBOX];          // 4.25 KB
    __shared__ int sufP[NBINS + 1];
    __shared__ int scanT[NBINS];                  // tail scratch
    __shared__ ull binFG[BINCAP];                 // 8 KB
    __shared__ ull binBG[BINCAP];                 // 8 KB
    __shared__ __align__(16) ull selKeys[BATCH + 2];
    __shared__ int waveTot[16], waveOff[16];
    __shared__ int cntF, cntB, cntSel, sTF, sTB;

    // load keys + clear selA: strided, covers the 4256-elem array incl. tail
    for (int i0 = tid * 4; i0 < KBOX; i0 += 1024 * 4) {
        ulonglong2 a = *(const ulonglong2*)(keysG + (size_t)b * KBOX + i0);
        ulonglong2 c = *(const ulonglong2*)(keysG + (size_t)b * KBOX + i0 + 2);
        *(ulonglong2*)&keys[i0]     = a;
        *(ulonglong2*)&keys[i0 + 2] = c;
        *(uchar4*)&selA[i0] = make_uchar4(0, 0, 0, 0);
    }
    // histogram: sum per-chunk slices
    int hv = 0;
    #pragma unroll
    for (int c = 0; c < KCHB; ++c) hv += histG[((size_t)(b * KCHB + c)) * NBINS + tid];
    if (tid == 0) { cntF = 0; cntB = 0; cntSel = 0; sTF = -1; sTB = -1; }

    // inclusive suffix scan of packed histogram: wave shfl + cross-wave
    int v = hv;
    #pragma unroll
    for (int off = 1; off < 64; off <<= 1) {
        int o = __shfl_down(v, off);
        if (lane + off < 64) v += o;
    }
    if (lane == 0) waveTot[wv] = v;   // wave total (suffix at lane 0)
    __syncthreads();
    if (wv == 0) {
        int t = (lane < 16) ? waveTot[lane] : 0;
        #pragma unroll
        for (int off = 1; off < 64; off <<= 1) {
            int o = __shfl_down(t, off);
            if (lane + off < 64) t += o;
        }
        if (lane < 16) waveOff[lane] = t - waveTot[lane];  // strict suffix
    }
    __syncthreads();
    sufP[tid] = v + waveOff[wv];
    if (tid == 0) sufP[NBINS] = 0;
    __syncthreads();

    const int total_fg = sufP[0] & 0xFFFF;
    const int total_bg = (sufP[0] >> 16) & 0xFFFF;
    const int num_fg = min(total_fg, NFG_CAP);
    const int num_bg = min(total_bg, BATCH - num_fg);

    {
        int sf  = sufP[tid] & 0xFFFF;
        int sfn = sufP[tid + 1] & 0xFFFF;
        if (num_fg > 0 && sf >= num_fg && sfn < num_fg) sTF = tid;
        int sb  = (sufP[tid] >> 16) & 0xFFFF;
        int sbn = (sufP[tid + 1] >> 16) & 0xFFFF;
        if (num_bg > 0 && sb >= num_bg && sbn < num_bg) sTB = tid;
    }
    __syncthreads();
    const int tF = sTF, tB = sTB;
    const int aboveF = (tF >= 0) ? (sufP[tF + 1] & 0xFFFF) : 0;
    const int aboveB = (tB >= 0) ? ((sufP[tB + 1] >> 16) & 0xFFFF) : 0;
    const int needF = num_fg - aboveF;
    const int needB = num_bg - aboveB;

    // selection: above threshold bin -> selected; in threshold bin -> collect
    for (int i = tid; i < KBOX; i += 1024) {
        ull key = keys[i];
        float p = __uint_as_float((unsigned)(key >> 32));
        int bucket = (int)(p * (float)NBINS);
        bucket = min(max(bucket, 0), NBINS - 1);
        bool fg = ((unsigned)(key >> 8) & 0xFFu) < NCLS;
        if (fg) {
            if (tF >= 0) {
                if (bucket > tF) selA[i] = 1;
                else if (bucket == tF) { int j = atomicAdd(&cntF, 1); if (j < BINCAP) binFG[j] = key; }
            }
        } else {
            if (tB >= 0) {
                if (bucket > tB) selA[i] = 1;
                else if (bucket == tB) { int j = atomicAdd(&cntB, 1); if (j < BINCAP) binBG[j] = key; }
            }
        }
    }
    __syncthreads();

    // exact rank inside threshold bins (keys distinct)
    {
        int cf = min(cntF, BINCAP);
        for (int j = tid; j < cf; j += 1024) {
            ull key = binFG[j];
            int rank = 0;
            for (int l = 0; l < cf; ++l) rank += (binFG[l] > key) ? 1 : 0;
            if (rank < needF) { unsigned kk = 0xFFFFu - (unsigned)((key >> 16) & 0xFFFFu); selA[kk] = 1; }
        }
        int cb = min(cntB, BINCAP);
        for (int j = tid; j < cb; j += 1024) {
            ull key = binBG[j];
            int rank = 0;
            for (int l = 0; l < cb; ++l) rank += (binBG[l] > key) ? 1 : 0;
            if (rank < needB) { unsigned kk = 0xFFFFu - (unsigned)((key >> 16) & 0xFFFFu); selA[kk] = 1; }
        }
    }
    __syncthreads();

    // compact selected keys
    for (int i = tid; i < KBOX; i += 1024) {
        if (selA[i]) {
            int p = atomicAdd(&cntSel, 1);
            selKeys[p] = keys[i];
        }
    }
    __syncthreads();
    const int ns = cntSel;      // == num_fg + num_bg
    if (tid == 0) { selKeys[ns] = 0ull; selKeys[ns + 1] = 0ull; }  // pad for vec reads
    __syncthreads();

    // order by rank-counting (no barriers, LDS broadcast reads)
    if (tid < ns) {
        ull key = selKeys[tid];
        int rank = 0;
        const int n2 = (ns + 1) & ~1;
        for (int l = 0; l < n2; l += 2) {
            ulonglong2 two = *(const ulonglong2*)&selKeys[l];
            rank += (two.x > key) ? 1 : 0;
            rank += (two.y > key) ? 1 : 0;
        }
        unsigned kk = 0xFFFFu - (unsigned)((key >> 16) & 0xFFFFu);
        int cls = (int)((key >> 8) & 0xFFu);
        out_idx[b * BATCH + rank] = (float)kk;
        out_lab[b * BATCH + rank] = (float)cls;
    }

    // tail padding (labels = -1): lowest-index non-selected (dormant when ns==512)
    if (ns < BATCH) {
        __syncthreads();
        int loc[5]; int acc = 0;
        #pragma unroll
        for (int q = 0; q < 5; ++q) {
            int i = tid * 5 + q;
            int contrib = (i < KBOX && !selA[i]) ? 1 : 0;
            loc[q] = acc; acc += contrib;
        }
        scanT[tid] = acc;
        __syncthreads();
        for (int off = 1; off < 1024; off <<= 1) {
            int vv = scanT[tid];
            int add = (tid >= off) ? scanT[tid - off] : 0;
            __syncthreads();
            scanT[tid] = vv + add;
            __syncthreads();
        }
        int excl = tid ? scanT[tid - 1] : 0;
        #pragma unroll
        for (int q = 0; q < 5; ++q) {
            int i = tid * 5 + q;
            if (i < KBOX && !selA[i]) {
                int p = ns + excl + loc[q];
                if (p < BATCH) { out_idx[b * BATCH + p] = (float)i; out_lab[b * BATCH + p] = -1.0f; }
            }
        }
    }
}

extern "C" void kernel_launch(void* const* d_in, const int* in_sizes, int n_in,
                              void* d_out, int out_size, void* d_ws, size_t ws_size,
                              hipStream_t stream) {
    const float* gt_boxes   = (const float*)d_in[0];
    const float* prop_boxes = (const float*)d_in[1];
    const int*   gt_classes = (const int*)d_in[2];
    const float* rand_pri   = (const float*)d_in[3];

    float* out = (float*)d_out;
    const size_t off_iou  = 0;
    const size_t off_midx = (size_t)Bimg * Mgt * KBOX;
    const size_t off_mlab = off_midx + (size_t)Bimg * KBOX;
    const size_t off_idx  = off_mlab + (size_t)Bimg * KBOX;
    const size_t off_lab  = off_idx  + (size_t)Bimg * BATCH;

    // workspace layout (all fully overwritten every call)
    char* ws = (char*)d_ws;
    ull* part  = (ull*)ws;                                       // [B,MS,K]  8.72 MB
    ull* keysG = (ull*)(ws + (size_t)Bimg * MS * KBOX * 8);      // [B,K]     1.09 MB
    int* histG = (int*)(ws + (size_t)Bimg * MS * KBOX * 8
                           + (size_t)Bimg * KBOX * 8);           // [B,KCHB,NBINS] 1.18 MB

    dim3 gridA(NCHA, MS, Bimg);  // 8 x 8 x 32 = 2048 blocks = exactly 8 resident/CU
    iou_part_kernel<<<gridA, 256, 0, stream>>>(
        gt_boxes, prop_boxes, out + off_iou, part);

    dim3 gridD(KCHB, Bimg);      // 9 x 32 = 288 blocks
    decode_kernel<<<gridD, 256, 0, stream>>>(
        gt_classes, rand_pri, part,
        out + off_midx, out + off_mlab, keysG, histG);

    sample_kernel<<<Bimg, 1024, 0, stream>>>(
        keysG, histG, out + off_idx, out + off_lab);
}

// Round 11
// 63.347 us; speedup vs baseline: 1.2591x; 1.2591x over previous
//
#include <hip/hip_runtime.h>
#include <hip/hip_bf16.h>

#define Bimg 32
#define Mgt 256
#define Nprop 4000
#define KBOX (Nprop + Mgt)   // 4256
#define NCLS 80
#define BATCH 512
#define NFG_CAP 128
#define NBINS 1024
#define BINCAP 1024
#define KCHB ((KBOX + 511) / 512)   // 9 chunks (decode, 2/thread)

// config L (large ws): MT=16, CPT=4, 16B stores
#define MT_L 16
#define MS_L (Mgt / MT_L)           // 16 slices
#define KCH_L ((KBOX + 1023) / 1024)  // 5 chunks
// config S (small ws fallback = round 9): MT=32, CPT=2
#define MT_S 32
#define MS_S (Mgt / MT_S)           // 8 slices
#define KCH_S ((KBOX + 511) / 512)  // 9 chunks

typedef float f32x2 __attribute__((ext_vector_type(2)));
typedef float f32x4 __attribute__((ext_vector_type(4)));
typedef unsigned long long ull;

__device__ __forceinline__ float fast_iou(float inter, float uni) {
    // rcp + 1 Newton step (~1-2 ulp); uni >= 16 always, inter==0 -> exactly +0
    float r = __builtin_amdgcn_rcpf(uni);
    r = fmaf(fmaf(-uni, r, 1.0f), r, r);
    return inter * r;
}

// ---------------- Kernel A (config L): 4 cols/thread, f32x4 stores ----------------
__global__ __launch_bounds__(256) void iou_part4_kernel(
    const float* __restrict__ gt_boxes,     // [B,M,4]
    const float* __restrict__ prop_boxes,   // [B,N,4]
    float* __restrict__ out_iou,            // [B,M,K]
    ull* __restrict__ part)                 // [B,MS_L,K]
{
    const int b  = blockIdx.z;
    const int ms = blockIdx.y;
    const int m0 = ms * MT_L;
    const int k0 = (blockIdx.x * 256 + threadIdx.x) * 4;

    __shared__ float4 gbox[MT_L];
    __shared__ float  garea[MT_L];
    if (threadIdx.x < MT_L) {
        float4 g = ((const float4*)(gt_boxes + (size_t)b * Mgt * 4))[m0 + threadIdx.x];
        gbox[threadIdx.x] = g;
        garea[threadIdx.x] = (g.z - g.x) * (g.w - g.y);
    }
    __syncthreads();
    if (k0 >= KBOX) return;

    float4 bx[4]; float a2[4];
    if (k0 < Nprop) {   // k0 % 4 == 0, Nprop % 4 == 0 -> no straddle
        const float4* pp = (const float4*)(prop_boxes + (size_t)b * Nprop * 4);
        #pragma unroll
        for (int c = 0; c < 4; ++c) bx[c] = pp[k0 + c];
    } else {
        const float4* gg = (const float4*)(gt_boxes + (size_t)b * Mgt * 4);
        #pragma unroll
        for (int c = 0; c < 4; ++c) bx[c] = gg[k0 - Nprop + c];
    }
    #pragma unroll
    for (int c = 0; c < 4; ++c) a2[c] = (bx[c].z - bx[c].x) * (bx[c].w - bx[c].y);

    float bestv[4] = {-1.f, -1.f, -1.f, -1.f};
    int   bestm[4] = {0, 0, 0, 0};
    float* orow = out_iou + (size_t)b * Mgt * KBOX + (size_t)m0 * KBOX + k0;

    for (int mm = 0; mm < MT_L; ++mm) {
        float4 g = gbox[mm];
        float ga = garea[mm];
        float io[4];
        #pragma unroll
        for (int c = 0; c < 4; ++c) {
            float ltx = fmaxf(g.x, bx[c].x), lty = fmaxf(g.y, bx[c].y);
            float rbx = fminf(g.z, bx[c].z), rby = fminf(g.w, bx[c].w);
            float w = fmaxf(rbx - ltx, 0.0f), h = fmaxf(rby - lty, 0.0f);
            float inter = w * h;
            float iou = fast_iou(inter, ga + a2[c] - inter);
            io[c] = iou;
            if (iou > bestv[c]) { bestv[c] = iou; bestm[c] = m0 + mm; }  // strict > == first-argmax
        }
        f32x4 res = { io[0], io[1], io[2], io[3] };
        *(f32x4*)(orow + (size_t)mm * KBOX) = res;
    }

    ull* pr = part + ((size_t)b * MS_L + ms) * KBOX + k0;
    ull bk[4];
    #pragma unroll
    for (int c = 0; c < 4; ++c)
        bk[c] = ((ull)__float_as_uint(bestv[c]) << 8) | (ull)(255 - bestm[c]);
    *(ulonglong2*)(pr)     = make_ulonglong2(bk[0], bk[1]);
    *(ulonglong2*)(pr + 2) = make_ulonglong2(bk[2], bk[3]);
}

// ---------------- Kernel A (config S = round 9): 2 cols/thread ----------------
__global__ __launch_bounds__(256) void iou_part2_kernel(
    const float* __restrict__ gt_boxes,
    const float* __restrict__ prop_boxes,
    float* __restrict__ out_iou,
    ull* __restrict__ part)                 // [B,MS_S,K]
{
    const int b  = blockIdx.z;
    const int ms = blockIdx.y;
    const int m0 = ms * MT_S;
    const int k0 = (blockIdx.x * 256 + threadIdx.x) * 2;

    __shared__ float4 gbox[MT_S];
    __shared__ float  garea[MT_S];
    if (threadIdx.x < MT_S) {
        float4 g = ((const float4*)(gt_boxes + (size_t)b * Mgt * 4))[m0 + threadIdx.x];
        gbox[threadIdx.x] = g;
        garea[threadIdx.x] = (g.z - g.x) * (g.w - g.y);
    }
    __syncthreads();
    if (k0 >= KBOX) return;

    float4 bx0, bx1;
    if (k0 < Nprop) {
        const float4* pp = (const float4*)(prop_boxes + (size_t)b * Nprop * 4);
        bx0 = pp[k0]; bx1 = pp[k0 + 1];
    } else {
        const float4* gg = (const float4*)(gt_boxes + (size_t)b * Mgt * 4);
        bx0 = gg[k0 - Nprop]; bx1 = gg[k0 + 1 - Nprop];
    }
    const float a20 = (bx0.z - bx0.x) * (bx0.w - bx0.y);
    const float a21 = (bx1.z - bx1.x) * (bx1.w - bx1.y);

    float bestv0 = -1.f, bestv1 = -1.f;
    int   bestm0 = 0,    bestm1 = 0;
    float* orow = out_iou + (size_t)b * Mgt * KBOX + (size_t)m0 * KBOX + k0;

    for (int mm = 0; mm < MT_S; ++mm) {
        float4 g = gbox[mm];
        float ga = garea[mm];
        float ltx0 = fmaxf(g.x, bx0.x), lty0 = fmaxf(g.y, bx0.y);
        float rbx0 = fminf(g.z, bx0.z), rby0 = fminf(g.w, bx0.w);
        float inter0 = fmaxf(rbx0 - ltx0, 0.0f) * fmaxf(rby0 - lty0, 0.0f);
        float io0 = fast_iou(inter0, ga + a20 - inter0);
        float ltx1 = fmaxf(g.x, bx1.x), lty1 = fmaxf(g.y, bx1.y);
        float rbx1 = fminf(g.z, bx1.z), rby1 = fminf(g.w, bx1.w);
        float inter1 = fmaxf(rbx1 - ltx1, 0.0f) * fmaxf(rby1 - lty1, 0.0f);
        float io1 = fast_iou(inter1, ga + a21 - inter1);

        if (io0 > bestv0) { bestv0 = io0; bestm0 = m0 + mm; }
        if (io1 > bestv1) { bestv1 = io1; bestm1 = m0 + mm; }

        f32x2 res = { io0, io1 };
        *(f32x2*)(orow + (size_t)mm * KBOX) = res;
    }

    ull bk0 = ((ull)__float_as_uint(bestv0) << 8) | (ull)(255 - bestm0);
    ull bk1 = ((ull)__float_as_uint(bestv1) << 8) | (ull)(255 - bestm1);
    *(ulonglong2*)(part + ((size_t)b * MS_S + ms) * KBOX + k0) = make_ulonglong2(bk0, bk1);
}

// ---------------- Kernel B1: parallel decode + keys + per-block histograms ----------------
__global__ __launch_bounds__(256) void decode_kernel(
    const int*   __restrict__ gt_classes,   // [B,M]
    const float* __restrict__ pri,          // [B,K]
    const ull*   __restrict__ part,         // [B,nslice,K]
    int nslice,
    float* __restrict__ out_midx,           // [B,K]
    float* __restrict__ out_mlab,           // [B,K]
    ull*   __restrict__ keysG,              // [B,K]
    int*   __restrict__ histG)              // [B,KCHB,NBINS] packed fg|bg
{
    const int b   = blockIdx.y;
    const int ch  = blockIdx.x;
    const int tid = threadIdx.x;

    __shared__ int histL[NBINS];
    __shared__ int gcls[Mgt];
    *(int4*)&histL[tid * 4] = make_int4(0, 0, 0, 0);
    gcls[tid] = gt_classes[b * Mgt + tid];
    __syncthreads();

    const int i0 = ch * 512 + tid * 2;
    if (i0 < KBOX) {
        const ull* p0 = part + (size_t)b * nslice * KBOX + i0;
        ulonglong2 bk2 = *(const ulonglong2*)p0;
        ull bk[2] = { bk2.x, bk2.y };
        for (int s = 1; s < nslice; ++s) {
            ulonglong2 t = *(const ulonglong2*)(p0 + (size_t)s * KBOX);
            bk[0] = (t.x > bk[0]) ? t.x : bk[0];
            bk[1] = (t.y > bk[1]) ? t.y : bk[1];
        }
        f32x2 pv = *(const f32x2*)(pri + (size_t)b * KBOX + i0);
        float mi2[2], ml2[2]; ull kk[2];
        #pragma unroll
        for (int c = 0; c < 2; ++c) {
            float v  = __uint_as_float((unsigned)(bk[c] >> 8));
            int   mi = 255 - (int)(bk[c] & 0xFFull);
            bool  fg = (v >= 0.5f);
            int  cls = fg ? gcls[mi] : NCLS;
            mi2[c] = (float)mi;
            ml2[c] = fg ? 1.0f : 0.0f;
            float p = pv[c];
            unsigned pb = __float_as_uint(p);   // pri in [0,1): monotone as uint
            kk[c] = ((ull)pb << 32) |
                    ((ull)(0xFFFFu - (unsigned)(i0 + c)) << 16) |
                    ((ull)(unsigned)cls << 8);
            int bucket = (int)(p * (float)NBINS);
            bucket = min(max(bucket, 0), NBINS - 1);
            atomicAdd(&histL[bucket], fg ? 1 : (1 << 16));
        }
        *(f32x2*)(out_midx + (size_t)b * KBOX + i0) = f32x2{ mi2[0], mi2[1] };
        *(f32x2*)(out_mlab + (size_t)b * KBOX + i0) = f32x2{ ml2[0], ml2[1] };
        *(ulonglong2*)(keysG + (size_t)b * KBOX + i0) = make_ulonglong2(kk[0], kk[1]);
    }
    __syncthreads();
    int4 h = *(int4*)&histL[tid * 4];
    *(int4*)&histG[((size_t)(b * KCHB + ch)) * NBINS + tid * 4] = h;
}

// ---------------- Kernel B2: scan + select + rank-order (1 block / image) ----------------
__global__ __launch_bounds__(1024) void sample_kernel(
    const ull* __restrict__ keysG,          // [B,K]
    const int* __restrict__ histG,          // [B,KCHB,NBINS]
    float* __restrict__ out_idx,            // [B,512]
    float* __restrict__ out_lab)            // [B,512]
{
    const int b    = blockIdx.x;
    const int tid  = threadIdx.x;
    const int lane = tid & 63;
    const int wv   = tid >> 6;              // 16 waves

    __shared__ ull keys[KBOX];                    // 34 KB
    __shared__ unsigned char selA[KBOX];          // 4.25 KB
    __shared__ int sufP[NBINS + 1];
    __shared__ int scanT[NBINS];                  // tail scratch
    __shared__ ull binFG[BINCAP];                 // 8 KB
    __shared__ ull binBG[BINCAP];                 // 8 KB
    __shared__ __align__(16) ull selKeys[BATCH + 2];
    __shared__ int waveTot[16], waveOff[16];
    __shared__ int cntF, cntB, cntSel, sTF, sTB;

    // load keys + clear selA: strided, covers the 4256-elem array incl. tail
    for (int i0 = tid * 4; i0 < KBOX; i0 += 1024 * 4) {
        ulonglong2 a = *(const ulonglong2*)(keysG + (size_t)b * KBOX + i0);
        ulonglong2 c = *(const ulonglong2*)(keysG + (size_t)b * KBOX + i0 + 2);
        *(ulonglong2*)&keys[i0]     = a;
        *(ulonglong2*)&keys[i0 + 2] = c;
        *(uchar4*)&selA[i0] = make_uchar4(0, 0, 0, 0);
    }
    // histogram: sum per-chunk slices
    int hv = 0;
    #pragma unroll
    for (int c = 0; c < KCHB; ++c) hv += histG[((size_t)(b * KCHB + c)) * NBINS + tid];
    if (tid == 0) { cntF = 0; cntB = 0; cntSel = 0; sTF = -1; sTB = -1; }

    // inclusive suffix scan of packed histogram: wave shfl + cross-wave
    int v = hv;
    #pragma unroll
    for (int off = 1; off < 64; off <<= 1) {
        int o = __shfl_down(v, off);
        if (lane + off < 64) v += o;
    }
    if (lane == 0) waveTot[wv] = v;   // wave total (suffix at lane 0)
    __syncthreads();
    if (wv == 0) {
        int t = (lane < 16) ? waveTot[lane] : 0;
        #pragma unroll
        for (int off = 1; off < 64; off <<= 1) {
            int o = __shfl_down(t, off);
            if (lane + off < 64) t += o;
        }
        if (lane < 16) waveOff[lane] = t - waveTot[lane];  // strict suffix
    }
    __syncthreads();
    sufP[tid] = v + waveOff[wv];
    if (tid == 0) sufP[NBINS] = 0;
    __syncthreads();

    const int total_fg = sufP[0] & 0xFFFF;
    const int total_bg = (sufP[0] >> 16) & 0xFFFF;
    const int num_fg = min(total_fg, NFG_CAP);
    const int num_bg = min(total_bg, BATCH - num_fg);

    {
        int sf  = sufP[tid] & 0xFFFF;
        int sfn = sufP[tid + 1] & 0xFFFF;
        if (num_fg > 0 && sf >= num_fg && sfn < num_fg) sTF = tid;
        int sb  = (sufP[tid] >> 16) & 0xFFFF;
        int sbn = (sufP[tid + 1] >> 16) & 0xFFFF;
        if (num_bg > 0 && sb >= num_bg && sbn < num_bg) sTB = tid;
    }
    __syncthreads();
    const int tF = sTF, tB = sTB;
    const int aboveF = (tF >= 0) ? (sufP[tF + 1] & 0xFFFF) : 0;
    const int aboveB = (tB >= 0) ? ((sufP[tB + 1] >> 16) & 0xFFFF) : 0;
    const int needF = num_fg - aboveF;
    const int needB = num_bg - aboveB;

    // selection: above threshold bin -> selected; in threshold bin -> collect
    for (int i = tid; i < KBOX; i += 1024) {
        ull key = keys[i];
        float p = __uint_as_float((unsigned)(key >> 32));
        int bucket = (int)(p * (float)NBINS);
        bucket = min(max(bucket, 0), NBINS - 1);
        bool fg = ((unsigned)(key >> 8) & 0xFFu) < NCLS;
        if (fg) {
            if (tF >= 0) {
                if (bucket > tF) selA[i] = 1;
                else if (bucket == tF) { int j = atomicAdd(&cntF, 1); if (j < BINCAP) binFG[j] = key; }
            }
        } else {
            if (tB >= 0) {
                if (bucket > tB) selA[i] = 1;
                else if (bucket == tB) { int j = atomicAdd(&cntB, 1); if (j < BINCAP) binBG[j] = key; }
            }
        }
    }
    __syncthreads();

    // exact rank inside threshold bins (keys distinct)
    {
        int cf = min(cntF, BINCAP);
        for (int j = tid; j < cf; j += 1024) {
            ull key = binFG[j];
            int rank = 0;
            for (int l = 0; l < cf; ++l) rank += (binFG[l] > key) ? 1 : 0;
            if (rank < needF) { unsigned kk = 0xFFFFu - (unsigned)((key >> 16) & 0xFFFFu); selA[kk] = 1; }
        }
        int cb = min(cntB, BINCAP);
        for (int j = tid; j < cb; j += 1024) {
            ull key = binBG[j];
            int rank = 0;
            for (int l = 0; l < cb; ++l) rank += (binBG[l] > key) ? 1 : 0;
            if (rank < needB) { unsigned kk = 0xFFFFu - (unsigned)((key >> 16) & 0xFFFFu); selA[kk] = 1; }
        }
    }
    __syncthreads();

    // compact selected keys
    for (int i = tid; i < KBOX; i += 1024) {
        if (selA[i]) {
            int p = atomicAdd(&cntSel, 1);
            selKeys[p] = keys[i];
        }
    }
    __syncthreads();
    const int ns = cntSel;      // == num_fg + num_bg
    if (tid == 0) { selKeys[ns] = 0ull; selKeys[ns + 1] = 0ull; }  // pad for vec reads
    __syncthreads();

    // order by rank-counting (no barriers, LDS broadcast reads)
    if (tid < ns) {
        ull key = selKeys[tid];
        int rank = 0;
        const int n2 = (ns + 1) & ~1;
        for (int l = 0; l < n2; l += 2) {
            ulonglong2 two = *(const ulonglong2*)&selKeys[l];
            rank += (two.x > key) ? 1 : 0;
            rank += (two.y > key) ? 1 : 0;
        }
        unsigned kk = 0xFFFFu - (unsigned)((key >> 16) & 0xFFFFu);
        int cls = (int)((key >> 8) & 0xFFu);
        out_idx[b * BATCH + rank] = (float)kk;
        out_lab[b * BATCH + rank] = (float)cls;
    }

    // tail padding (labels = -1): lowest-index non-selected (dormant when ns==512)
    if (ns < BATCH) {
        __syncthreads();
        int loc[5]; int acc = 0;
        #pragma unroll
        for (int q = 0; q < 5; ++q) {
            int i = tid * 5 + q;
            int contrib = (i < KBOX && !selA[i]) ? 1 : 0;
            loc[q] = acc; acc += contrib;
        }
        scanT[tid] = acc;
        __syncthreads();
        for (int off = 1; off < 1024; off <<= 1) {
            int vv = scanT[tid];
            int add = (tid >= off) ? scanT[tid - off] : 0;
            __syncthreads();
            scanT[tid] = vv + add;
            __syncthreads();
        }
        int excl = tid ? scanT[tid - 1] : 0;
        #pragma unroll
        for (int q = 0; q < 5; ++q) {
            int i = tid * 5 + q;
            if (i < KBOX && !selA[i]) {
                int p = ns + excl + loc[q];
                if (p < BATCH) { out_idx[b * BATCH + p] = (float)i; out_lab[b * BATCH + p] = -1.0f; }
            }
        }
    }
}

extern "C" void kernel_launch(void* const* d_in, const int* in_sizes, int n_in,
                              void* d_out, int out_size, void* d_ws, size_t ws_size,
                              hipStream_t stream) {
    const float* gt_boxes   = (const float*)d_in[0];
    const float* prop_boxes = (const float*)d_in[1];
    const int*   gt_classes = (const int*)d_in[2];
    const float* rand_pri   = (const float*)d_in[3];

    float* out = (float*)d_out;
    const size_t off_iou  = 0;
    const size_t off_midx = (size_t)Bimg * Mgt * KBOX;
    const size_t off_mlab = off_midx + (size_t)Bimg * KBOX;
    const size_t off_idx  = off_mlab + (size_t)Bimg * KBOX;
    const size_t off_lab  = off_idx  + (size_t)Bimg * BATCH;

    const size_t keys_bytes = (size_t)Bimg * KBOX * 8;            // 1.09 MB
    const size_t hist_bytes = (size_t)Bimg * KCHB * NBINS * 4;    // 1.18 MB
    const size_t partL_bytes = (size_t)Bimg * MS_L * KBOX * 8;    // 17.4 MB
    const bool bigws = ws_size >= partL_bytes + keys_bytes + hist_bytes;

    char* ws = (char*)d_ws;
    ull* part = (ull*)ws;
    const size_t part_bytes = bigws ? partL_bytes : (size_t)Bimg * MS_S * KBOX * 8;
    ull* keysG = (ull*)(ws + part_bytes);
    int* histG = (int*)(ws + part_bytes + keys_bytes);

    if (bigws) {
        dim3 gridA(KCH_L, MS_L, Bimg);   // 5 x 16 x 32 = 2560 blocks, 16B stores
        iou_part4_kernel<<<gridA, 256, 0, stream>>>(
            gt_boxes, prop_boxes, out + off_iou, part);
    } else {
        dim3 gridA(KCH_S, MS_S, Bimg);   // 9 x 8 x 32 = 2304 blocks, 8B stores
        iou_part2_kernel<<<gridA, 256, 0, stream>>>(
            gt_boxes, prop_boxes, out + off_iou, part);
    }

    dim3 gridD(KCHB, Bimg);      // 9 x 32 = 288 blocks
    decode_kernel<<<gridD, 256, 0, stream>>>(
        gt_classes, rand_pri, part, bigws ? MS_L : MS_S,
        out + off_midx, out + off_mlab, keysG, histG);

    sample_kernel<<<Bimg, 1024, 0, stream>>>(
        keysG, histG, out + off_idx, out + off_lab);
}

// Round 12
// 60.301 us; speedup vs baseline: 1.3227x; 1.0505x over previous
//
#include <hip/hip_runtime.h>
#include <hip/hip_bf16.h>

#define Bimg 32
#define Mgt 256
#define Nprop 4000
#define KBOX (Nprop + Mgt)   // 4256
#define NCLS 80
#define BATCH 512
#define NFG_CAP 128
#define NBINS 1024
#define BINCAP 1024
#define MT 32                 // m-rows per block
#define MS (Mgt / MT)         // 8 m-slices
#define KCHB ((KBOX + 511) / 512)   // 9 chunks (decode, 2/thread)

typedef float f32x2 __attribute__((ext_vector_type(2)));
typedef unsigned long long ull;

__device__ __forceinline__ float fast_iou(float inter, float uni) {
    // rcp + 1 Newton step (~1-2 ulp); uni >= 16 always, inter==0 -> exactly +0
    float r = __builtin_amdgcn_rcpf(uni);
    r = fmaf(fmaf(-uni, r, 1.0f), r, r);
    return inter * r;
}

// ---------------- Kernel A: IoU tiles + per-slice partial argmax ----------------
// Exact-2048 grid: 8 column chunks, widths {544,544,528x6}, all 64B-aligned starts.
__global__ __launch_bounds__(256) void iou_part_kernel(
    const float* __restrict__ gt_boxes,     // [B,M,4]
    const float* __restrict__ prop_boxes,   // [B,N,4]
    float* __restrict__ out_iou,            // [B,M,K]
    ull* __restrict__ part)                 // [B,MS,K] packed keys
{
    const int b  = blockIdx.z;
    const int ms = blockIdx.y;
    const int m0 = ms * MT;
    const int c  = blockIdx.x;
    const int start = c * 528 + min(c, 2) * 16;      // 64B-aligned (x4B)
    const int nu    = (528 + ((c < 2) ? 16 : 0)) >> 1;  // 272 or 264 units

    __shared__ float4 gbox[MT];
    __shared__ float  garea[MT];
    if (threadIdx.x < MT) {
        float4 g = ((const float4*)(gt_boxes + (size_t)b * Mgt * 4))[m0 + threadIdx.x];
        gbox[threadIdx.x] = g;
        garea[threadIdx.x] = (g.z - g.x) * (g.w - g.y);
    }
    __syncthreads();

    for (int u = threadIdx.x; u < nu; u += 256) {
        const int k0 = start + 2 * u;   // even; prop/gt boundary (4000 even) never straddled

        float4 bx0, bx1;
        if (k0 < Nprop) {
            const float4* pp = (const float4*)(prop_boxes + (size_t)b * Nprop * 4);
            bx0 = pp[k0]; bx1 = pp[k0 + 1];
        } else {
            const float4* gg = (const float4*)(gt_boxes + (size_t)b * Mgt * 4);
            bx0 = gg[k0 - Nprop]; bx1 = gg[k0 + 1 - Nprop];
        }
        const float a20 = (bx0.z - bx0.x) * (bx0.w - bx0.y);
        const float a21 = (bx1.z - bx1.x) * (bx1.w - bx1.y);

        float bestv0 = -1.f, bestv1 = -1.f;
        int   bestm0 = 0,    bestm1 = 0;
        float* orow = out_iou + (size_t)b * Mgt * KBOX + (size_t)m0 * KBOX + k0;

        for (int mm = 0; mm < MT; ++mm) {
            float4 g = gbox[mm];
            float ga = garea[mm];
            float ltx0 = fmaxf(g.x, bx0.x), lty0 = fmaxf(g.y, bx0.y);
            float rbx0 = fminf(g.z, bx0.z), rby0 = fminf(g.w, bx0.w);
            float inter0 = fmaxf(rbx0 - ltx0, 0.0f) * fmaxf(rby0 - lty0, 0.0f);
            float io0 = fast_iou(inter0, ga + a20 - inter0);
            float ltx1 = fmaxf(g.x, bx1.x), lty1 = fmaxf(g.y, bx1.y);
            float rbx1 = fminf(g.z, bx1.z), rby1 = fminf(g.w, bx1.w);
            float inter1 = fmaxf(rbx1 - ltx1, 0.0f) * fmaxf(rby1 - lty1, 0.0f);
            float io1 = fast_iou(inter1, ga + a21 - inter1);

            if (io0 > bestv0) { bestv0 = io0; bestm0 = m0 + mm; }  // strict > == first-argmax
            if (io1 > bestv1) { bestv1 = io1; bestm1 = m0 + mm; }

            f32x2 res = { io0, io1 };
            *(f32x2*)(orow + (size_t)mm * KBOX) = res;
        }

        ull bk0 = ((ull)__float_as_uint(bestv0) << 8) | (ull)(255 - bestm0);
        ull bk1 = ((ull)__float_as_uint(bestv1) << 8) | (ull)(255 - bestm1);
        *(ulonglong2*)(part + ((size_t)b * MS + ms) * KBOX + k0) =
            make_ulonglong2(bk0, bk1);   // max-key == (max iou, min m)
    }
}

// ---------------- Kernel B1: parallel decode + keys + per-block histograms ----------------
__global__ __launch_bounds__(256) void decode_kernel(
    const int*   __restrict__ gt_classes,   // [B,M]
    const float* __restrict__ pri,          // [B,K]
    const ull*   __restrict__ part,         // [B,MS,K]
    float* __restrict__ out_midx,           // [B,K]
    float* __restrict__ out_mlab,           // [B,K]
    ull*   __restrict__ keysG,              // [B,K]
    int*   __restrict__ histG)              // [B,KCHB,NBINS] packed fg|bg
{
    const int b   = blockIdx.y;
    const int ch  = blockIdx.x;
    const int tid = threadIdx.x;

    __shared__ int histL[NBINS];
    __shared__ int gcls[Mgt];
    *(int4*)&histL[tid * 4] = make_int4(0, 0, 0, 0);
    gcls[tid] = gt_classes[b * Mgt + tid];
    __syncthreads();

    const int i0 = ch * 512 + tid * 2;
    if (i0 < KBOX) {
        const ull* p0 = part + (size_t)b * MS * KBOX + i0;
        ulonglong2 bk2 = *(const ulonglong2*)p0;
        ull bk[2] = { bk2.x, bk2.y };
        #pragma unroll
        for (int s = 1; s < MS; ++s) {
            ulonglong2 t = *(const ulonglong2*)(p0 + (size_t)s * KBOX);
            bk[0] = (t.x > bk[0]) ? t.x : bk[0];
            bk[1] = (t.y > bk[1]) ? t.y : bk[1];
        }
        f32x2 pv = *(const f32x2*)(pri + (size_t)b * KBOX + i0);
        float mi2[2], ml2[2]; ull kk[2];
        #pragma unroll
        for (int c = 0; c < 2; ++c) {
            float v  = __uint_as_float((unsigned)(bk[c] >> 8));
            int   mi = 255 - (int)(bk[c] & 0xFFull);
            bool  fg = (v >= 0.5f);
            int  cls = fg ? gcls[mi] : NCLS;
            mi2[c] = (float)mi;
            ml2[c] = fg ? 1.0f : 0.0f;
            float p = pv[c];
            unsigned pb = __float_as_uint(p);   // pri in [0,1): monotone as uint
            kk[c] = ((ull)pb << 32) |
                    ((ull)(0xFFFFu - (unsigned)(i0 + c)) << 16) |
                    ((ull)(unsigned)cls << 8);
            int bucket = (int)(p * (float)NBINS);
            bucket = min(max(bucket, 0), NBINS - 1);
            atomicAdd(&histL[bucket], fg ? 1 : (1 << 16));
        }
        *(f32x2*)(out_midx + (size_t)b * KBOX + i0) = f32x2{ mi2[0], mi2[1] };
        *(f32x2*)(out_mlab + (size_t)b * KBOX + i0) = f32x2{ ml2[0], ml2[1] };
        *(ulonglong2*)(keysG + (size_t)b * KBOX + i0) = make_ulonglong2(kk[0], kk[1]);
    }
    __syncthreads();
    int4 h = *(int4*)&histL[tid * 4];
    *(int4*)&histG[((size_t)(b * KCHB + ch)) * NBINS + tid * 4] = h;
}

// ---------------- Kernel B2: scan + select + rank-order (1 block / image) ----------------
__global__ __launch_bounds__(1024) void sample_kernel(
    const ull* __restrict__ keysG,          // [B,K]
    const int* __restrict__ histG,          // [B,KCHB,NBINS]
    float* __restrict__ out_idx,            // [B,512]
    float* __restrict__ out_lab)            // [B,512]
{
    const int b    = blockIdx.x;
    const int tid  = threadIdx.x;
    const int lane = tid & 63;
    const int wv   = tid >> 6;              // 16 waves

    __shared__ ull keys[KBOX];                    // 34 KB
    __shared__ unsigned char selA[KBOX];          // 4.25 KB
    __shared__ int sufP[NBINS + 1];
    __shared__ int scanT[NBINS];                  // tail scratch
    __shared__ ull binFG[BINCAP];                 // 8 KB
    __shared__ ull binBG[BINCAP];                 // 8 KB
    __shared__ __align__(16) ull selKeys[BATCH + 2];
    __shared__ int waveTot[16], waveOff[16];
    __shared__ int cntF, cntB, cntSel, sTF, sTB;

    // load keys + clear selA: strided, covers the 4256-elem array incl. tail
    for (int i0 = tid * 4; i0 < KBOX; i0 += 1024 * 4) {
        ulonglong2 a = *(const ulonglong2*)(keysG + (size_t)b * KBOX + i0);
        ulonglong2 c = *(const ulonglong2*)(keysG + (size_t)b * KBOX + i0 + 2);
        *(ulonglong2*)&keys[i0]     = a;
        *(ulonglong2*)&keys[i0 + 2] = c;
        *(uchar4*)&selA[i0] = make_uchar4(0, 0, 0, 0);
    }
    // histogram: sum per-chunk slices
    int hv = 0;
    #pragma unroll
    for (int c = 0; c < KCHB; ++c) hv += histG[((size_t)(b * KCHB + c)) * NBINS + tid];
    if (tid == 0) { cntF = 0; cntB = 0; cntSel = 0; sTF = -1; sTB = -1; }

    // inclusive suffix scan of packed histogram: wave shfl + cross-wave
    int v = hv;
    #pragma unroll
    for (int off = 1; off < 64; off <<= 1) {
        int o = __shfl_down(v, off);
        if (lane + off < 64) v += o;
    }
    if (lane == 0) waveTot[wv] = v;   // wave total (suffix at lane 0)
    __syncthreads();
    if (wv == 0) {
        int t = (lane < 16) ? waveTot[lane] : 0;
        #pragma unroll
        for (int off = 1; off < 64; off <<= 1) {
            int o = __shfl_down(t, off);
            if (lane + off < 64) t += o;
        }
        if (lane < 16) waveOff[lane] = t - waveTot[lane];  // strict suffix
    }
    __syncthreads();
    sufP[tid] = v + waveOff[wv];
    if (tid == 0) sufP[NBINS] = 0;
    __syncthreads();

    const int total_fg = sufP[0] & 0xFFFF;
    const int total_bg = (sufP[0] >> 16) & 0xFFFF;
    const int num_fg = min(total_fg, NFG_CAP);
    const int num_bg = min(total_bg, BATCH - num_fg);

    {
        int sf  = sufP[tid] & 0xFFFF;
        int sfn = sufP[tid + 1] & 0xFFFF;
        if (num_fg > 0 && sf >= num_fg && sfn < num_fg) sTF = tid;
        int sb  = (sufP[tid] >> 16) & 0xFFFF;
        int sbn = (sufP[tid + 1] >> 16) & 0xFFFF;
        if (num_bg > 0 && sb >= num_bg && sbn < num_bg) sTB = tid;
    }
    __syncthreads();
    const int tF = sTF, tB = sTB;
    const int aboveF = (tF >= 0) ? (sufP[tF + 1] & 0xFFFF) : 0;
    const int aboveB = (tB >= 0) ? ((sufP[tB + 1] >> 16) & 0xFFFF) : 0;
    const int needF = num_fg - aboveF;
    const int needB = num_bg - aboveB;

    // selection: above threshold bin -> selected; in threshold bin -> collect
    for (int i = tid; i < KBOX; i += 1024) {
        ull key = keys[i];
        float p = __uint_as_float((unsigned)(key >> 32));
        int bucket = (int)(p * (float)NBINS);
        bucket = min(max(bucket, 0), NBINS - 1);
        bool fg = ((unsigned)(key >> 8) & 0xFFu) < NCLS;
        if (fg) {
            if (tF >= 0) {
                if (bucket > tF) selA[i] = 1;
                else if (bucket == tF) { int j = atomicAdd(&cntF, 1); if (j < BINCAP) binFG[j] = key; }
            }
        } else {
            if (tB >= 0) {
                if (bucket > tB) selA[i] = 1;
                else if (bucket == tB) { int j = atomicAdd(&cntB, 1); if (j < BINCAP) binBG[j] = key; }
            }
        }
    }
    __syncthreads();

    // exact rank inside threshold bins (keys distinct)
    {
        int cf = min(cntF, BINCAP);
        for (int j = tid; j < cf; j += 1024) {
            ull key = binFG[j];
            int rank = 0;
            for (int l = 0; l < cf; ++l) rank += (binFG[l] > key) ? 1 : 0;
            if (rank < needF) { unsigned kk = 0xFFFFu - (unsigned)((key >> 16) & 0xFFFFu); selA[kk] = 1; }
        }
        int cb = min(cntB, BINCAP);
        for (int j = tid; j < cb; j += 1024) {
            ull key = binBG[j];
            int rank = 0;
            for (int l = 0; l < cb; ++l) rank += (binBG[l] > key) ? 1 : 0;
            if (rank < needB) { unsigned kk = 0xFFFFu - (unsigned)((key >> 16) & 0xFFFFu); selA[kk] = 1; }
        }
    }
    __syncthreads();

    // compact selected keys
    for (int i = tid; i < KBOX; i += 1024) {
        if (selA[i]) {
            int p = atomicAdd(&cntSel, 1);
            selKeys[p] = keys[i];
        }
    }
    __syncthreads();
    const int ns = cntSel;      // == num_fg + num_bg
    if (tid == 0) { selKeys[ns] = 0ull; selKeys[ns + 1] = 0ull; }  // pad for vec reads
    __syncthreads();

    // order by rank-counting (no barriers, LDS broadcast reads)
    if (tid < ns) {
        ull key = selKeys[tid];
        int rank = 0;
        const int n2 = (ns + 1) & ~1;
        for (int l = 0; l < n2; l += 2) {
            ulonglong2 two = *(const ulonglong2*)&selKeys[l];
            rank += (two.x > key) ? 1 : 0;
            rank += (two.y > key) ? 1 : 0;
        }
        unsigned kk = 0xFFFFu - (unsigned)((key >> 16) & 0xFFFFu);
        int cls = (int)((key >> 8) & 0xFFu);
        out_idx[b * BATCH + rank] = (float)kk;
        out_lab[b * BATCH + rank] = (float)cls;
    }

    // tail padding (labels = -1): lowest-index non-selected (dormant when ns==512)
    if (ns < BATCH) {
        __syncthreads();
        int loc[5]; int acc = 0;
        #pragma unroll
        for (int q = 0; q < 5; ++q) {
            int i = tid * 5 + q;
            int contrib = (i < KBOX && !selA[i]) ? 1 : 0;
            loc[q] = acc; acc += contrib;
        }
        scanT[tid] = acc;
        __syncthreads();
        for (int off = 1; off < 1024; off <<= 1) {
            int vv = scanT[tid];
            int add = (tid >= off) ? scanT[tid - off] : 0;
            __syncthreads();
            scanT[tid] = vv + add;
            __syncthreads();
        }
        int excl = tid ? scanT[tid - 1] : 0;
        #pragma unroll
        for (int q = 0; q < 5; ++q) {
            int i = tid * 5 + q;
            if (i < KBOX && !selA[i]) {
                int p = ns + excl + loc[q];
                if (p < BATCH) { out_idx[b * BATCH + p] = (float)i; out_lab[b * BATCH + p] = -1.0f; }
            }
        }
    }
}

extern "C" void kernel_launch(void* const* d_in, const int* in_sizes, int n_in,
                              void* d_out, int out_size, void* d_ws, size_t ws_size,
                              hipStream_t stream) {
    const float* gt_boxes   = (const float*)d_in[0];
    const float* prop_boxes = (const float*)d_in[1];
    const int*   gt_classes = (const int*)d_in[2];
    const float* rand_pri   = (const float*)d_in[3];

    float* out = (float*)d_out;
    const size_t off_iou  = 0;
    const size_t off_midx = (size_t)Bimg * Mgt * KBOX;
    const size_t off_mlab = off_midx + (size_t)Bimg * KBOX;
    const size_t off_idx  = off_mlab + (size_t)Bimg * KBOX;
    const size_t off_lab  = off_idx  + (size_t)Bimg * BATCH;

    // workspace layout (all fully overwritten every call)
    char* ws = (char*)d_ws;
    ull* part  = (ull*)ws;                                       // [B,MS,K]  8.72 MB
    ull* keysG = (ull*)(ws + (size_t)Bimg * MS * KBOX * 8);      // [B,K]     1.09 MB
    int* histG = (int*)(ws + (size_t)Bimg * MS * KBOX * 8
                           + (size_t)Bimg * KBOX * 8);           // [B,KCHB,NBINS] 1.18 MB

    dim3 gridA(8, MS, Bimg);     // 8 x 8 x 32 = 2048 blocks = exactly 8 resident/CU
    iou_part_kernel<<<gridA, 256, 0, stream>>>(
        gt_boxes, prop_boxes, out + off_iou, part);

    dim3 gridD(KCHB, Bimg);      // 9 x 32 = 288 blocks
    decode_kernel<<<gridD, 256, 0, stream>>>(
        gt_classes, rand_pri, part,
        out + off_midx, out + off_mlab, keysG, histG);

    sample_kernel<<<Bimg, 1024, 0, stream>>>(
        keysG, histG, out + off_idx, out + off_lab);
}

// Round 13
// 56.247 us; speedup vs baseline: 1.4180x; 1.0721x over previous
//
#include <hip/hip_runtime.h>
#include <hip/hip_bf16.h>

#define Bimg 32
#define Mgt 256
#define Nprop 4000
#define KBOX (Nprop + Mgt)   // 4256
#define NCLS 80
#define BATCH 512
#define NFG_CAP 128
#define NBINS 1024
#define BINCAP 1024
#define MT 32                 // m-rows per block
#define MS (Mgt / MT)         // 8 m-slices
#define CPT 2                 // columns per thread (kernel A)
#define KCH ((KBOX + 256*CPT - 1) / (256*CPT))  // 9 column chunks (A)
#define KCHB ((KBOX + 511) / 512)               // 9 chunks (decode, 2/thread)

typedef float f32x2 __attribute__((ext_vector_type(2)));
typedef unsigned long long ull;

__device__ __forceinline__ float fast_iou(float inter, float uni) {
    // rcp + 1 Newton step (~1-2 ulp); uni >= 16 always, inter==0 -> exactly +0
    float r = __builtin_amdgcn_rcpf(uni);
    r = fmaf(fmaf(-uni, r, 1.0f), r, r);
    return inter * r;
}

// ---------------- Kernel A: IoU tiles + per-slice partial argmax ----------------
__global__ __launch_bounds__(256) void iou_part_kernel(
    const float* __restrict__ gt_boxes,     // [B,M,4]
    const float* __restrict__ prop_boxes,   // [B,N,4]
    float* __restrict__ out_iou,            // [B,M,K]
    ull* __restrict__ part)                 // [B,MS,K] packed keys
{
    const int b  = blockIdx.z;
    const int ms = blockIdx.y;
    const int m0 = ms * MT;
    const int k0 = (blockIdx.x * 256 + threadIdx.x) * CPT;

    __shared__ float4 gbox[MT];
    __shared__ float  garea[MT];
    if (threadIdx.x < MT) {
        float4 g = ((const float4*)(gt_boxes + (size_t)b * Mgt * 4))[m0 + threadIdx.x];
        gbox[threadIdx.x] = g;
        garea[threadIdx.x] = (g.z - g.x) * (g.w - g.y);
    }
    __syncthreads();
    if (k0 >= KBOX) return;

    float4 bx0, bx1;
    if (k0 < Nprop) {   // k0 even, Nprop even -> no straddle
        const float4* pp = (const float4*)(prop_boxes + (size_t)b * Nprop * 4);
        bx0 = pp[k0]; bx1 = pp[k0 + 1];
    } else {
        const float4* gg = (const float4*)(gt_boxes + (size_t)b * Mgt * 4);
        bx0 = gg[k0 - Nprop]; bx1 = gg[k0 + 1 - Nprop];
    }
    const float a20 = (bx0.z - bx0.x) * (bx0.w - bx0.y);
    const float a21 = (bx1.z - bx1.x) * (bx1.w - bx1.y);

    float bestv0 = -1.f, bestv1 = -1.f;
    int   bestm0 = 0,    bestm1 = 0;
    float* orow = out_iou + (size_t)b * Mgt * KBOX + (size_t)m0 * KBOX + k0;

    for (int mm = 0; mm < MT; ++mm) {
        float4 g = gbox[mm];
        float ga = garea[mm];
        float ltx0 = fmaxf(g.x, bx0.x), lty0 = fmaxf(g.y, bx0.y);
        float rbx0 = fminf(g.z, bx0.z), rby0 = fminf(g.w, bx0.w);
        float inter0 = fmaxf(rbx0 - ltx0, 0.0f) * fmaxf(rby0 - lty0, 0.0f);
        float io0 = fast_iou(inter0, ga + a20 - inter0);
        float ltx1 = fmaxf(g.x, bx1.x), lty1 = fmaxf(g.y, bx1.y);
        float rbx1 = fminf(g.z, bx1.z), rby1 = fminf(g.w, bx1.w);
        float inter1 = fmaxf(rbx1 - ltx1, 0.0f) * fmaxf(rby1 - lty1, 0.0f);
        float io1 = fast_iou(inter1, ga + a21 - inter1);

        if (io0 > bestv0) { bestv0 = io0; bestm0 = m0 + mm; }  // strict > == first-argmax
        if (io1 > bestv1) { bestv1 = io1; bestm1 = m0 + mm; }

        f32x2 res = { io0, io1 };
        *(f32x2*)(orow + (size_t)mm * KBOX) = res;
    }

    ull bk0 = ((ull)__float_as_uint(bestv0) << 8) | (ull)(255 - bestm0);
    ull bk1 = ((ull)__float_as_uint(bestv1) << 8) | (ull)(255 - bestm1);
    *(ulonglong2*)(part + ((size_t)b * MS + ms) * KBOX + k0) =
        make_ulonglong2(bk0, bk1);   // max-key == (max iou, min m)
}

// ---------------- Kernel B1: parallel decode + keys + per-block histograms ----------------
__global__ __launch_bounds__(256) void decode_kernel(
    const int*   __restrict__ gt_classes,   // [B,M]
    const float* __restrict__ pri,          // [B,K]
    const ull*   __restrict__ part,         // [B,MS,K]
    float* __restrict__ out_midx,           // [B,K]
    float* __restrict__ out_mlab,           // [B,K]
    ull*   __restrict__ keysG,              // [B,K]
    int*   __restrict__ histG)              // [B,KCHB,NBINS] packed fg|bg
{
    const int b   = blockIdx.y;
    const int ch  = blockIdx.x;
    const int tid = threadIdx.x;

    __shared__ int histL[NBINS];
    __shared__ int gcls[Mgt];
    *(int4*)&histL[tid * 4] = make_int4(0, 0, 0, 0);
    gcls[tid] = gt_classes[b * Mgt + tid];
    __syncthreads();

    const int i0 = ch * 512 + tid * 2;
    if (i0 < KBOX) {
        const ull* p0 = part + (size_t)b * MS * KBOX + i0;
        ulonglong2 bk2 = *(const ulonglong2*)p0;
        ull bk[2] = { bk2.x, bk2.y };
        #pragma unroll
        for (int s = 1; s < MS; ++s) {
            ulonglong2 t = *(const ulonglong2*)(p0 + (size_t)s * KBOX);
            bk[0] = (t.x > bk[0]) ? t.x : bk[0];
            bk[1] = (t.y > bk[1]) ? t.y : bk[1];
        }
        f32x2 pv = *(const f32x2*)(pri + (size_t)b * KBOX + i0);
        float mi2[2], ml2[2]; ull kk[2];
        #pragma unroll
        for (int c = 0; c < 2; ++c) {
            float v  = __uint_as_float((unsigned)(bk[c] >> 8));
            int   mi = 255 - (int)(bk[c] & 0xFFull);
            bool  fg = (v >= 0.5f);
            int  cls = fg ? gcls[mi] : NCLS;
            mi2[c] = (float)mi;
            ml2[c] = fg ? 1.0f : 0.0f;
            float p = pv[c];
            unsigned pb = __float_as_uint(p);   // pri in [0,1): monotone as uint
            kk[c] = ((ull)pb << 32) |
                    ((ull)(0xFFFFu - (unsigned)(i0 + c)) << 16) |
                    ((ull)(unsigned)cls << 8);
            int bucket = (int)(p * (float)NBINS);
            bucket = min(max(bucket, 0), NBINS - 1);
            atomicAdd(&histL[bucket], fg ? 1 : (1 << 16));
        }
        *(f32x2*)(out_midx + (size_t)b * KBOX + i0) = f32x2{ mi2[0], mi2[1] };
        *(f32x2*)(out_mlab + (size_t)b * KBOX + i0) = f32x2{ ml2[0], ml2[1] };
        *(ulonglong2*)(keysG + (size_t)b * KBOX + i0) = make_ulonglong2(kk[0], kk[1]);
    }
    __syncthreads();
    int4 h = *(int4*)&histL[tid * 4];
    *(int4*)&histG[((size_t)(b * KCHB + ch)) * NBINS + tid * 4] = h;
}

// ---------------- Kernel B2: scan + select + rank-order (1 block / image) ----------------
__global__ __launch_bounds__(1024) void sample_kernel(
    const ull* __restrict__ keysG,          // [B,K]
    const int* __restrict__ histG,          // [B,KCHB,NBINS]
    float* __restrict__ out_idx,            // [B,512]
    float* __restrict__ out_lab)            // [B,512]
{
    const int b    = blockIdx.x;
    const int tid  = threadIdx.x;
    const int lane = tid & 63;
    const int wv   = tid >> 6;              // 16 waves

    __shared__ ull keys[KBOX];                    // 34 KB
    __shared__ unsigned char selA[KBOX];          // 4.25 KB
    __shared__ int sufP[NBINS + 1];
    __shared__ int scanT[NBINS];                  // tail scratch
    __shared__ ull binFG[BINCAP];                 // 8 KB
    __shared__ ull binBG[BINCAP];                 // 8 KB
    __shared__ __align__(16) ull selKeys[BATCH + 2];
    __shared__ int waveTot[16], waveOff[16];
    __shared__ int cntF, cntB, cntSel, sTF, sTB;

    // load keys + clear selA: strided, covers the 4256-elem array incl. tail
    for (int i0 = tid * 4; i0 < KBOX; i0 += 1024 * 4) {
        ulonglong2 a = *(const ulonglong2*)(keysG + (size_t)b * KBOX + i0);
        ulonglong2 c = *(const ulonglong2*)(keysG + (size_t)b * KBOX + i0 + 2);
        *(ulonglong2*)&keys[i0]     = a;
        *(ulonglong2*)&keys[i0 + 2] = c;
        *(uchar4*)&selA[i0] = make_uchar4(0, 0, 0, 0);
    }
    // histogram: sum per-chunk slices
    int hv = 0;
    #pragma unroll
    for (int c = 0; c < KCHB; ++c) hv += histG[((size_t)(b * KCHB + c)) * NBINS + tid];
    if (tid == 0) { cntF = 0; cntB = 0; cntSel = 0; sTF = -1; sTB = -1; }

    // inclusive suffix scan of packed histogram: wave shfl + cross-wave
    int v = hv;
    #pragma unroll
    for (int off = 1; off < 64; off <<= 1) {
        int o = __shfl_down(v, off);
        if (lane + off < 64) v += o;
    }
    if (lane == 0) waveTot[wv] = v;   // wave total (suffix at lane 0)
    __syncthreads();
    if (wv == 0) {
        int t = (lane < 16) ? waveTot[lane] : 0;
        #pragma unroll
        for (int off = 1; off < 64; off <<= 1) {
            int o = __shfl_down(t, off);
            if (lane + off < 64) t += o;
        }
        if (lane < 16) waveOff[lane] = t - waveTot[lane];  // strict suffix
    }
    __syncthreads();
    sufP[tid] = v + waveOff[wv];
    if (tid == 0) sufP[NBINS] = 0;
    __syncthreads();

    const int total_fg = sufP[0] & 0xFFFF;
    const int total_bg = (sufP[0] >> 16) & 0xFFFF;
    const int num_fg = min(total_fg, NFG_CAP);
    const int num_bg = min(total_bg, BATCH - num_fg);

    {
        int sf  = sufP[tid] & 0xFFFF;
        int sfn = sufP[tid + 1] & 0xFFFF;
        if (num_fg > 0 && sf >= num_fg && sfn < num_fg) sTF = tid;
        int sb  = (sufP[tid] >> 16) & 0xFFFF;
        int sbn = (sufP[tid + 1] >> 16) & 0xFFFF;
        if (num_bg > 0 && sb >= num_bg && sbn < num_bg) sTB = tid;
    }
    __syncthreads();
    const int tF = sTF, tB = sTB;
    const int aboveF = (tF >= 0) ? (sufP[tF + 1] & 0xFFFF) : 0;
    const int aboveB = (tB >= 0) ? ((sufP[tB + 1] >> 16) & 0xFFFF) : 0;
    const int needF = num_fg - aboveF;
    const int needB = num_bg - aboveB;

    // selection: above threshold bin -> selected; in threshold bin -> collect
    for (int i = tid; i < KBOX; i += 1024) {
        ull key = keys[i];
        float p = __uint_as_float((unsigned)(key >> 32));
        int bucket = (int)(p * (float)NBINS);
        bucket = min(max(bucket, 0), NBINS - 1);
        bool fg = ((unsigned)(key >> 8) & 0xFFu) < NCLS;
        if (fg) {
            if (tF >= 0) {
                if (bucket > tF) selA[i] = 1;
                else if (bucket == tF) { int j = atomicAdd(&cntF, 1); if (j < BINCAP) binFG[j] = key; }
            }
        } else {
            if (tB >= 0) {
                if (bucket > tB) selA[i] = 1;
                else if (bucket == tB) { int j = atomicAdd(&cntB, 1); if (j < BINCAP) binBG[j] = key; }
            }
        }
    }
    __syncthreads();

    // exact rank inside threshold bins (keys distinct)
    {
        int cf = min(cntF, BINCAP);
        for (int j = tid; j < cf; j += 1024) {
            ull key = binFG[j];
            int rank = 0;
            for (int l = 0; l < cf; ++l) rank += (binFG[l] > key) ? 1 : 0;
            if (rank < needF) { unsigned kk = 0xFFFFu - (unsigned)((key >> 16) & 0xFFFFu); selA[kk] = 1; }
        }
        int cb = min(cntB, BINCAP);
        for (int j = tid; j < cb; j += 1024) {
            ull key = binBG[j];
            int rank = 0;
            for (int l = 0; l < cb; ++l) rank += (binBG[l] > key) ? 1 : 0;
            if (rank < needB) { unsigned kk = 0xFFFFu - (unsigned)((key >> 16) & 0xFFFFu); selA[kk] = 1; }
        }
    }
    __syncthreads();

    // compact selected keys
    for (int i = tid; i < KBOX; i += 1024) {
        if (selA[i]) {
            int p = atomicAdd(&cntSel, 1);
            selKeys[p] = keys[i];
        }
    }
    __syncthreads();
    const int ns = cntSel;      // == num_fg + num_bg
    if (tid == 0) { selKeys[ns] = 0ull; selKeys[ns + 1] = 0ull; }  // pad for vec reads
    __syncthreads();

    // order by rank-counting (no barriers, LDS broadcast reads)
    if (tid < ns) {
        ull key = selKeys[tid];
        int rank = 0;
        const int n2 = (ns + 1) & ~1;
        for (int l = 0; l < n2; l += 2) {
            ulonglong2 two = *(const ulonglong2*)&selKeys[l];
            rank += (two.x > key) ? 1 : 0;
            rank += (two.y > key) ? 1 : 0;
        }
        unsigned kk = 0xFFFFu - (unsigned)((key >> 16) & 0xFFFFu);
        int cls = (int)((key >> 8) & 0xFFu);
        out_idx[b * BATCH + rank] = (float)kk;
        out_lab[b * BATCH + rank] = (float)cls;
    }

    // tail padding (labels = -1): lowest-index non-selected (dormant when ns==512)
    if (ns < BATCH) {
        __syncthreads();
        int loc[5]; int acc = 0;
        #pragma unroll
        for (int q = 0; q < 5; ++q) {
            int i = tid * 5 + q;
            int contrib = (i < KBOX && !selA[i]) ? 1 : 0;
            loc[q] = acc; acc += contrib;
        }
        scanT[tid] = acc;
        __syncthreads();
        for (int off = 1; off < 1024; off <<= 1) {
            int vv = scanT[tid];
            int add = (tid >= off) ? scanT[tid - off] : 0;
            __syncthreads();
            scanT[tid] = vv + add;
            __syncthreads();
        }
        int excl = tid ? scanT[tid - 1] : 0;
        #pragma unroll
        for (int q = 0; q < 5; ++q) {
            int i = tid * 5 + q;
            if (i < KBOX && !selA[i]) {
                int p = ns + excl + loc[q];
                if (p < BATCH) { out_idx[b * BATCH + p] = (float)i; out_lab[b * BATCH + p] = -1.0f; }
            }
        }
    }
}

extern "C" void kernel_launch(void* const* d_in, const int* in_sizes, int n_in,
                              void* d_out, int out_size, void* d_ws, size_t ws_size,
                              hipStream_t stream) {
    const float* gt_boxes   = (const float*)d_in[0];
    const float* prop_boxes = (const float*)d_in[1];
    const int*   gt_classes = (const int*)d_in[2];
    const float* rand_pri   = (const float*)d_in[3];

    float* out = (float*)d_out;
    const size_t off_iou  = 0;
    const size_t off_midx = (size_t)Bimg * Mgt * KBOX;
    const size_t off_mlab = off_midx + (size_t)Bimg * KBOX;
    const size_t off_idx  = off_mlab + (size_t)Bimg * KBOX;
    const size_t off_lab  = off_idx  + (size_t)Bimg * BATCH;

    // workspace layout (all fully overwritten every call)
    char* ws = (char*)d_ws;
    ull* part  = (ull*)ws;                                       // [B,MS,K]  8.72 MB
    ull* keysG = (ull*)(ws + (size_t)Bimg * MS * KBOX * 8);      // [B,K]     1.09 MB
    int* histG = (int*)(ws + (size_t)Bimg * MS * KBOX * 8
                           + (size_t)Bimg * KBOX * 8);           // [B,KCHB,NBINS] 1.18 MB

    dim3 gridA(KCH, MS, Bimg);   // 9 x 8 x 32 = 2304 blocks
    iou_part_kernel<<<gridA, 256, 0, stream>>>(
        gt_boxes, prop_boxes, out + off_iou, part);

    dim3 gridD(KCHB, Bimg);      // 9 x 32 = 288 blocks
    decode_kernel<<<gridD, 256, 0, stream>>>(
        gt_classes, rand_pri, part,
        out + off_midx, out + off_mlab, keysG, histG);

    sample_kernel<<<Bimg, 1024, 0, stream>>>(
        keysG, histG, out + off_idx, out + off_lab);
}